// Round 15
// baseline (55.811 us; speedup 1.0000x reference)
//
#include <hip/hip_runtime.h>
#include <math.h>

#define N_STEPS 10240
#define ENV_N 327744       // N_FRAMES*32
#define LCH 16             // chunk length (640 blocks)

typedef float f4a __attribute__((ext_vector_type(4), aligned(4)));

__device__ inline float2 mkf2(float x, float y) { return make_float2(x, y); }

// ---------------- wave-level complex FFT-256: 64 lanes, 4 float2 regs -------
template<int DIR>
__device__ inline void waveFFT256(float2 v[4], const int l,
                                  const float Tc, const float Ts,
                                  const float ux, const float uy) {
  const int rb = (int)(__brev((unsigned)l) >> 26);
  #pragma unroll
  for (int r = 0; r < 4; ++r) {
    v[r].x = __shfl(v[r].x, rb);
    v[r].y = __shfl(v[r].y, rb);
  }
  #pragma unroll
  for (int s = 0; s < 6; ++s) {
    const int half = 1 << s;
    float wx, wy;
    if (s == 0) { wx = (l & 1) ? -1.f : 1.f; wy = 0.f; }
    else {
      const int idx = (l << (5 - s)) & 63;
      wx = __shfl(Tc, idx);
      float tsv = __shfl(Ts, idx);
      wy = (DIR < 0) ? tsv : -tsv;
    }
    #pragma unroll
    for (int r = 0; r < 4; ++r) {
      float tx = __shfl_xor(v[r].x, half);
      float ty = __shfl_xor(v[r].y, half);
      const bool low = (l & half) == 0;
      float ax = low ? v[r].x : tx, ay = low ? v[r].y : ty;
      float bx = low ? tx : v[r].x, by = low ? ty : v[r].y;
      v[r].x = ax + (wx * bx - wy * by);
      v[r].y = ay + (wx * by + wy * bx);
    }
  }
  const float u2x = ux * ux - uy * uy, u2y = 2.f * ux * uy;
  const float u3x = u2x * ux - u2y * uy, u3y = u2x * uy + u2y * ux;
  float2 t0 = v[0];
  float2 t1 = mkf2(v[1].x * ux - v[1].y * uy, v[1].x * uy + v[1].y * ux);
  float2 t2 = mkf2(v[2].x * u2x - v[2].y * u2y, v[2].x * u2y + v[2].y * u2x);
  float2 t3 = mkf2(v[3].x * u3x - v[3].y * u3y, v[3].x * u3y + v[3].y * u3x);
  float2 p02 = mkf2(t0.x + t2.x, t0.y + t2.y), m02 = mkf2(t0.x - t2.x, t0.y - t2.y);
  float2 p13 = mkf2(t1.x + t3.x, t1.y + t3.y), m13 = mkf2(t1.x - t3.x, t1.y - t3.y);
  v[0] = mkf2(p02.x + p13.x, p02.y + p13.y);
  v[2] = mkf2(p02.x - p13.x, p02.y - p13.y);
  if (DIR < 0) {
    v[1] = mkf2(m02.x + m13.y, m02.y - m13.x);
    v[3] = mkf2(m02.x - m13.y, m02.y + m13.x);
  } else {
    v[1] = mkf2(m02.x - m13.y, m02.y + m13.x);
    v[3] = mkf2(m02.x + m13.y, m02.y - m13.x);
  }
}

// ---------------- forward row: excitation -> impulse spectrum into LDS ------
// (kernA body verbatim; twiddles precomputed per-lane by the caller)
__device__ inline void impRow(int j, int l, float2* __restrict__ row,
                              const float* __restrict__ env,
                              const float* __restrict__ noise,
                              const float* __restrict__ etf_re,
                              const float* __restrict__ etf_im,
                              float ca, float sa, float ux, float uy,
                              float Tc, float Ts) {
  const int K = 32 * j + l;
  float e0 = env[K];                e0 *= e0;
  float em = env[max(K - 1, 0)];    em *= em;
  float ep = env[min(K + 1, ENV_N - 1)]; ep *= ep;
  float sm[8];
  #pragma unroll
  for (int u = 0; u < 8; ++u) {
    float val;
    if (u < 4) {
      float fr = 0.5625f + 0.125f * (float)u;
      val = em * (1.f - fr) + e0 * fr;
      if (K == 0) val = e0;              // ref clamps coords at 0
    } else {
      float fr = 0.0625f + 0.125f * (float)(u - 4);
      val = e0 * (1.f - fr) + ep * fr;
    }
    sm[u] = val;
  }
  const float4* np = (const float4*)(noise + (size_t)j * 512 + 8 * l);
  float4 n0 = np[0], n1 = np[1];
  float nn[8] = {n0.x, n0.y, n0.z, n0.w, n1.x, n1.y, n1.z, n1.w};
  float2 v[4];
  #pragma unroll
  for (int r = 0; r < 4; ++r)
    v[r] = mkf2(nn[2 * r] * sm[2 * r], nn[2 * r + 1] * sm[2 * r + 1]);

  waveFFT256<-1>(v, l, Tc, Ts, ux, uy);  // v[r] = Z[64r + l]

  float2 Zc[4];
  const int pidx = (64 - l) & 63;
  #pragma unroll
  for (int r = 0; r < 4; ++r) {
    Zc[r].x = __shfl(v[3 - r].x, pidx);
    Zc[r].y = __shfl(v[3 - r].y, pidx);
  }
  float2 z0lane = v[0];
  if (l == 0) { Zc[0] = v[0]; Zc[1] = v[3]; Zc[2] = v[2]; Zc[3] = v[1]; }
  constexpr float crA[4] = {1.f, 0.7071067811865476f, 0.f, -0.7071067811865476f};
  constexpr float srA[4] = {0.f, -0.7071067811865476f, -1.f, -0.7071067811865476f};
  const float FS = 0.04419417382415922f;                  // 1/sqrt(512)
  #pragma unroll
  for (int r = 0; r < 4; ++r) {
    float Ex = 0.5f * (v[r].x + Zc[r].x), Ey = 0.5f * (v[r].y - Zc[r].y);
    float Dx = v[r].x - Zc[r].x,          Dy = v[r].y + Zc[r].y;
    float Ox = 0.5f * Dy, Oy = -0.5f * Dx;
    float c  = crA[r] * ca - srA[r] * sa;                 // e^{-i pi k/256}
    float sn = crA[r] * sa + srA[r] * ca;
    float Wx = (Ex + (c * Ox - sn * Oy)) * FS;
    float Wy = (Ey + (c * Oy + sn * Ox)) * FS;
    int k = 64 * r + l;
    float er = etf_re[k], ei = etf_im[k];
    float Px = Wx * er - Wy * ei;
    float Py = Wx * ei + Wy * er;
    if (k == 0) Py = 0.f;                // irfft drops Im at DC
    row[k] = mkf2(Px, Py);
  }
  if (l == 0) {
    float W256 = (z0lane.x - z0lane.y) * FS;
    row[256] = mkf2(W256 * etf_re[256], 0.f);
  }
}

// ---------------- scan pieces -----------------------------------------------
struct StepBuf { f4a tr, ti; };

__device__ inline void loadTF(StepBuf& b, int i, int l,
                              const float* __restrict__ tf_re,
                              const float* __restrict__ tf_im) {
  const size_t tb = (size_t)i * 257 + 4 * l;
  b.tr = *(const f4a*)(tf_re + tb);
  b.ti = *(const f4a*)(tf_im + tb);
}

__device__ inline void doStep(const StepBuf& b, const float4& ia, const float4& ib,
                              int l, float tfr256, float imp256,
                              float2& s0, float2& s1, float2& s2, float2& s3,
                              float& s256) {
  float2 y0, y1, y2, y3;
  y0.x = s0.x * b.tr[0] - s0.y * b.ti[0];  y0.y = s0.x * b.ti[0] + s0.y * b.tr[0];
  y1.x = s1.x * b.tr[1] - s1.y * b.ti[1];  y1.y = s1.x * b.ti[1] + s1.y * b.tr[1];
  y2.x = s2.x * b.tr[2] - s2.y * b.ti[2];  y2.y = s2.x * b.ti[2] + s2.y * b.tr[2];
  y3.x = s3.x * b.tr[3] - s3.y * b.ti[3];  y3.y = s3.x * b.ti[3] + s3.y * b.tr[3];
  if (l == 0) y0.y = 0.f;              // drop Im at DC (irfft semantics)
  float Y256 = tfr256 * s256;          // Nyquist, real
  float phx = __shfl_up(y3.x, 1), phy = __shfl_up(y3.y, 1);
  float nlx = __shfl_down(y0.x, 1), nly = __shfl_down(y0.y, 1);
  float2 p0 = (l == 0)  ? mkf2(y1.x, -y1.y) : mkf2(phx, phy);  // Y_{-1} = conj(Y_1)
  float2 n3 = (l == 63) ? mkf2(Y256, 0.f)   : mkf2(nlx, nly);  // Y_256 (real)
  float y255x = __shfl(y3.x, 63);
  const float A = 0.54f, Bc = 0.23f;
  float2 c0, c1, c2, c3;
  c0.x = A * y0.x - Bc * (p0.x + y1.x);  c0.y = A * y0.y - Bc * (p0.y + y1.y);
  c1.x = A * y1.x - Bc * (y0.x + y2.x);  c1.y = A * y1.y - Bc * (y0.y + y2.y);
  c2.x = A * y2.x - Bc * (y1.x + y3.x);  c2.y = A * y2.y - Bc * (y1.y + y3.y);
  c3.x = A * y3.x - Bc * (y2.x + n3.x);  c3.y = A * y3.y - Bc * (y2.y + n3.y);
  float C256 = A * Y256 - 0.46f * y255x;
  s0.x = c0.x + ia.x;  s0.y = c0.y + ia.y;
  s1.x = c1.x + ia.z;  s1.y = c1.y + ia.w;
  s2.x = c2.x + ib.x;  s2.y = c2.y + ib.y;
  s3.x = c3.x + ib.z;  s3.y = c3.y + ib.w;
  s256 = C256 + imp256;
}

// ---------------- fused kernel: impulse FFTs + scan + iFFT + OA -------------
// Block = 4 waves. Phase 1: waves compute the block's 24 (17 for c=0) impulse
// rows into LDS in parallel. Phase 2: all 4 waves run the scan redundantly
// (tf from global, 4-deep prefetch; IMP from LDS); wave w register-saves rows
// k == w (mod 4). Phase 3: each wave iFFTs its rows into ybuf (aliases the
// dead IMP LDS). Phase 4: overlap-add write of segments j0..j0+15.
__global__ __launch_bounds__(256, 2) void kernABC(const float* __restrict__ env,
                                                  const float* __restrict__ noise,
                                                  const float* __restrict__ tf_re,
                                                  const float* __restrict__ tf_im,
                                                  const float* __restrict__ etf_re,
                                                  const float* __restrict__ etf_im,
                                                  float* __restrict__ out) {
  const int c = blockIdx.x, tid = threadIdx.x;
  const int l = tid & 63, w = tid >> 6;
  const int j0 = c * LCH;
  const int w0 = (c > 0) ? (j0 - 9) : 0;       // 7 warm steps before first saved row
  const int lastStep = (c > 0) ? (j0 + 14) : 15;
  const int NR = (c > 0) ? 24 : 17;            // LDS impulse rows
  const int rowbase = (c > 0) ? (j0 - 8) : 0;  // local row t <-> global row rowbase+t
  const int IMPOFF = (c > 0) ? 0 : 1;          // step m consumes local row m+IMPOFF

  __shared__ float2 SH[24 * 258];              // 49.5 KB; aliased as ybuf later

  // early issue: tf prefetch + Nyquist tf gather (hide under phase 1)
  float t256v = tf_re[(size_t)min(w0 + l, N_STEPS - 1) * 257 + 256];
  StepBuf b0, b1, b2, b3;
  loadTF(b0, w0 + 0, l, tf_re, tf_im);
  loadTF(b1, w0 + 1, l, tf_re, tf_im);
  loadTF(b2, w0 + 2, l, tf_re, tf_im);
  loadTF(b3, w0 + 3, l, tf_re, tf_im);

  // all twiddles, once per lane
  float ca, sa; sincosf(-0.01227184630308513f * (float)l, &sa, &ca);  // fwd untangle
  const float ux = ca * ca - sa * sa, uy = 2.f * ca * sa;             // fwd u
  float Tc, Ts; sincosf(-0.09817477042468103f * (float)l, &Ts, &Tc);  // stage table
  float cu, su; sincosf(0.02454369260617026f * (float)l, &su, &cu);   // inv u
  const float clC = cu * cu - su * su, slC = 2.f * cu * su;           // inv untangle

  // ---- phase 1: impulse rows into LDS (wave w does rows t = w, w+4, ...) ---
  for (int t = w; t < NR; t += 4)
    impRow(rowbase + t, l, SH + t * 258, env, noise, etf_re, etf_im,
           ca, sa, ux, uy, Tc, Ts);
  __syncthreads();

  // per-lane preload of the imp256 series (lane m <-> step m)
  const float i256v = SH[(size_t)min(l + IMPOFF, NR - 1) * 258 + 256].x;

  float2 s0 = mkf2(0.f, 0.f), s1 = s0, s2 = s0, s3 = s0;
  float s256 = 0.f;
  float2 rs[5][4];                             // saved rows (static-indexed only)
  float rn[5];
  #pragma unroll
  for (int q = 0; q < 5; ++q) {
    rs[q][0] = rs[q][1] = rs[q][2] = rs[q][3] = mkf2(0.f, 0.f);
    rn[q] = 0.f;
  }

  if (c == 0) {                                // exact init: s = IMP row 0 (k=1)
    const float4* r4 = (const float4*)SH;      // local row 0
    float4 a = r4[2 * l], bb = r4[2 * l + 1];
    s0 = mkf2(a.x, a.y);  s1 = mkf2(a.z, a.w);
    s2 = mkf2(bb.x, bb.y); s3 = mkf2(bb.z, bb.w);
    s256 = SH[256].x;
    if (w == 1) { rs[0][0]=s0; rs[0][1]=s1; rs[0][2]=s2; rs[0][3]=s3; rn[0]=s256; }
  }

  #define SAVEIF(KK) \
    if ((KK) >= 0 && (KK) <= 16 && (((KK) & 3) == w)) { \
      const int _q = (((KK) > 0 ? (KK) : 0)) >> 2; \
      rs[_q][0]=s0; rs[_q][1]=s1; rs[_q][2]=s2; rs[_q][3]=s3; rn[_q]=s256; }

  #define STEP(BUF, M, KK) { \
    const float tfr_ = __shfl(t256v, (M)); \
    const float im2_ = __shfl(i256v, (M)); \
    const float4* ims = (const float4*)(SH + ((M) + IMPOFF) * 258); \
    const float4 ia = ims[2 * l]; \
    const float4 ib = ims[2 * l + 1]; \
    doStep(BUF, ia, ib, l, tfr_, im2_, s0, s1, s2, s3, s256); \
    SAVEIF(KK) \
    { int nx = w0 + (M) + 4; nx = (nx > lastStep) ? lastStep : nx; \
      loadTF(BUF, nx, l, tf_re, tf_im); } }

  if (c > 0) {                                 // 24 steps: 7 warm, k = m-7
    STEP(b0,0,-7)  STEP(b1,1,-6)  STEP(b2,2,-5)  STEP(b3,3,-4)
    STEP(b0,4,-3)  STEP(b1,5,-2)  STEP(b2,6,-1)  STEP(b3,7,0)
    STEP(b0,8,1)   STEP(b1,9,2)   STEP(b2,10,3)  STEP(b3,11,4)
    STEP(b0,12,5)  STEP(b1,13,6)  STEP(b2,14,7)  STEP(b3,15,8)
    STEP(b0,16,9)  STEP(b1,17,10) STEP(b2,18,11) STEP(b3,19,12)
    STEP(b0,20,13) STEP(b1,21,14) STEP(b2,22,15) STEP(b3,23,16)
  } else {                                     // 16 steps (last is padding), k = m+2
    STEP(b0,0,2)   STEP(b1,1,3)   STEP(b2,2,4)   STEP(b3,3,5)
    STEP(b0,4,6)   STEP(b1,5,7)   STEP(b2,6,8)   STEP(b3,7,9)
    STEP(b0,8,10)  STEP(b1,9,11)  STEP(b2,10,12) STEP(b3,11,13)
    STEP(b0,12,14) STEP(b1,13,15) STEP(b2,14,16) STEP(b3,15,17)
  }
  #undef STEP
  #undef SAVEIF

  __syncthreads();                             // all waves done READING IMP LDS

  // ---- phase 3: iFFT rows k = 4q + w into ybuf (aliases SH) ----------------
  float2 (*ybuf)[256] = (float2(*)[256])SH;    // 17*256 float2 = 34.8 KB < 49.5
  constexpr float crC[4] = {1.f, 0.9999247018391445f, 0.9996988186962042f, 0.9993223845883495f};
  constexpr float srC[4] = {0.f, 0.0122715382857199f, 0.0245412285229123f, 0.0368072229413588f};
  const float ISC = 0.08838834764831845f;      // sqrt(512)/256
  const int pidx = (64 - l) & 63;

  #pragma unroll
  for (int q = 0; q < 5; ++q) {
    const int k = 4 * q + w;
    if (k <= 16) {                             // wave-uniform condition
      float2 W0 = rs[q][0], W1 = rs[q][1], W2 = rs[q][2], W3 = rs[q][3];
      float w256 = rn[q];
      float2 W[4] = {W0, W1, W2, W3};
      float2 Wm[4];
      Wm[0].x = __shfl(W0.x, pidx);
      Wm[0].y = __shfl(W0.y, pidx);
      if (l == 0) Wm[0] = mkf2(w256, 0.f);
      Wm[1].x = __shfl_xor(W3.x, 63);  Wm[1].y = __shfl_xor(W3.y, 63);
      Wm[2].x = __shfl_xor(W2.x, 63);  Wm[2].y = __shfl_xor(W2.y, 63);
      Wm[3].x = __shfl_xor(W1.x, 63);  Wm[3].y = __shfl_xor(W1.y, 63);
      float2 v[4];
      #pragma unroll
      for (int rr = 0; rr < 4; ++rr) {
        float Ex = 0.5f * (W[rr].x + Wm[rr].x), Ey = 0.5f * (W[rr].y - Wm[rr].y);
        float Dx = W[rr].x - Wm[rr].x,          Dy = W[rr].y + Wm[rr].y;
        float cc  = clC * crC[rr] - slC * srC[rr];
        float sn  = clC * srC[rr] + slC * crC[rr];
        float Ox = 0.5f * (cc * Dx - sn * Dy);
        float Oy = 0.5f * (cc * Dy + sn * Dx);
        v[rr] = mkf2(Ex - Oy, Ey + Ox);
      }
      waveFFT256<+1>(v, l, Tc, Ts, cu, su);
      #pragma unroll
      for (int rr = 0; rr < 4; ++rr)
        ybuf[k][64 * rr + l] = mkf2(v[rr].x * ISC, v[rr].y * ISC);
    }
  }

  __syncthreads();

  // ---- phase 4: OA write: segment j0+k = ybuf[k+1] head + ybuf[k] tail -----
  float2* out2 = (float2*)out;
  const size_t base = (size_t)j0 * 128;
  for (int idx = tid; idx < 2048; idx += 256) {
    const int k = idx >> 7, t2 = idx & 127;
    float2 a = ybuf[k + 1][t2];
    float2 p = ybuf[k][128 + t2];
    out2[base + idx] = mkf2(a.x + p.x, a.y + p.y);
  }
}

// ---------------- launch ----------------
extern "C" void kernel_launch(void* const* d_in, const int* in_sizes, int n_in,
                              void* d_out, int out_size, void* d_ws, size_t ws_size,
                              hipStream_t stream) {
  const float* env    = (const float*)d_in[1];
  const float* tf_re  = (const float*)d_in[2];
  const float* tf_im  = (const float*)d_in[3];
  const float* etf_re = (const float*)d_in[4];
  const float* etf_im = (const float*)d_in[5];
  const float* noise  = (const float*)d_in[6];
  float* out = (float*)d_out;

  kernABC<<<N_STEPS / LCH, 256, 0, stream>>>(env, noise, tf_re, tf_im,
                                             etf_re, etf_im, out);
}